// Round 1
// baseline (42.398 us; speedup 1.0000x reference)
//
#include <hip/hip_runtime.h>

#define NMAPS 8
#define BATCH 32
#define DLEN  150528          // 3*224*224
#define D4    (DLEN / 4)      // 37632 float4 per (map, batch) row
#define NPAIR 36              // i<=j pairs among 8 maps (incl. diagonal = norm^2)
#define CHUNKS 32             // blocks per batch element
#define TPB   256

// Kernel 1: per batch element b, accumulate the 36 unique pairwise dot
// products of the 8 maps. Single pass over the 154 MB input (memory-bound).
__global__ __launch_bounds__(TPB) void gram_kernel(const float* __restrict__ x,
                                                   float* __restrict__ dots) {
    const int b     = blockIdx.x;   // 0..BATCH-1
    const int chunk = blockIdx.y;   // 0..CHUNKS-1
    const int tid   = threadIdx.x;

    const float4* xb = reinterpret_cast<const float4*>(x) + (size_t)b * D4;
    const size_t strideI = (size_t)BATCH * D4;  // float4 stride between maps

    float acc[NPAIR];
#pragma unroll
    for (int k = 0; k < NPAIR; ++k) acc[k] = 0.0f;

    for (int j = chunk * TPB + tid; j < D4; j += CHUNKS * TPB) {
        float4 v[NMAPS];
#pragma unroll
        for (int i = 0; i < NMAPS; ++i) v[i] = xb[(size_t)i * strideI + j];
        int k = 0;
#pragma unroll
        for (int i = 0; i < NMAPS; ++i) {
#pragma unroll
            for (int jj = i; jj < NMAPS; ++jj) {
                acc[k] += v[i].x * v[jj].x + v[i].y * v[jj].y +
                          v[i].z * v[jj].z + v[i].w * v[jj].w;
                ++k;
            }
        }
    }

    // wave (64-lane) shuffle reduction, then cross-wave LDS reduce
    const int lane = tid & 63;
    const int wave = tid >> 6;
    __shared__ float red[TPB / 64][NPAIR];
#pragma unroll
    for (int k = 0; k < NPAIR; ++k) {
        float s = acc[k];
#pragma unroll
        for (int off = 32; off > 0; off >>= 1) s += __shfl_down(s, off, 64);
        if (lane == 0) red[wave][k] = s;
    }
    __syncthreads();
    if (tid < NPAIR) {
        float t = red[0][tid] + red[1][tid] + red[2][tid] + red[3][tid];
        atomicAdd(&dots[b * NPAIR + tid], t);
    }
}

// Kernel 2: tiny epilogue. dots: [BATCH][NPAIR] (upper-tri incl diagonal).
__global__ __launch_bounds__(256) void finalize_kernel(const float* __restrict__ dots,
                                                       float* __restrict__ out) {
    const int tid = threadIdx.x;
    __shared__ float norms[BATCH][NMAPS];
    {
        int b = tid >> 3, i = tid & 7;              // 256 = 32*8 exactly
        int diag = 8 * i - (i * (i - 1)) / 2;       // upper-tri index of (i,i)
        norms[b][i] = sqrtf(dots[b * NPAIR + diag]);
    }
    __syncthreads();

    float sum = 0.0f;
    for (int item = tid; item < 28 * BATCH; item += 256) {
        int p = item >> 5;   // pair 0..27
        int b = item & 31;
        // decode p -> (i < j)
        int i = 0, rem = p;
        while (rem >= 7 - i) { rem -= 7 - i; ++i; }
        int j = i + 1 + rem;
        int k = 8 * i - (i * (i - 1)) / 2 + (j - i);
        float d   = fabsf(dots[b * NPAIR + k]);
        float den = fmaxf(norms[b][i] * norms[b][j], 1e-8f);
        sum += d / den;
    }

    const int lane = tid & 63, wave = tid >> 6;
    __shared__ float red[4];
#pragma unroll
    for (int off = 32; off > 0; off >>= 1) sum += __shfl_down(sum, off, 64);
    if (lane == 0) red[wave] = sum;
    __syncthreads();
    if (tid == 0) {
        out[0] = (red[0] + red[1] + red[2] + red[3]) / (28.0f * BATCH);
    }
}

extern "C" void kernel_launch(void* const* d_in, const int* in_sizes, int n_in,
                              void* d_out, int out_size, void* d_ws, size_t ws_size,
                              hipStream_t stream) {
    const float* x   = (const float*)d_in[0];
    float*       out = (float*)d_out;
    float*       dots = (float*)d_ws;   // BATCH*NPAIR floats = 4608 B

    hipMemsetAsync(dots, 0, BATCH * NPAIR * sizeof(float), stream);

    dim3 grid(BATCH, CHUNKS);
    gram_kernel<<<grid, TPB, 0, stream>>>(x, dots);
    finalize_kernel<<<1, 256, 0, stream>>>(dots, out);
}

// Round 2
// 41.361 us; speedup vs baseline: 1.0251x; 1.0251x over previous
//
#include <hip/hip_runtime.h>

#define NMAPS 8
#define BATCH 32
#define DLEN  150528          // 3*224*224
#define D4    (DLEN / 4)      // 37632 float4 per (map, batch) row
#define NPAIR 36              // i<=j pairs among 8 maps (incl. diagonal = norm^2)
#define CHUNKS 32             // blocks per batch element
#define TPB   256
#define JSTRIDE (CHUNKS * TPB)

// Kernel 1: per batch element b, accumulate the 36 unique pairwise dot
// products of the 8 maps. Single pass over the 154 MB input (memory-bound).
// Writes per-(chunk, b) partials to ws -- no memset, no atomics needed.
__global__ __launch_bounds__(TPB) void gram_kernel(const float* __restrict__ x,
                                                   float* __restrict__ partial) {
    const int b     = blockIdx.x;   // 0..BATCH-1
    const int chunk = blockIdx.y;   // 0..CHUNKS-1
    const int tid   = threadIdx.x;

    const float4* xb = reinterpret_cast<const float4*>(x) + (size_t)b * D4;
    const size_t strideI = (size_t)BATCH * D4;  // float4 stride between maps

    float acc[NPAIR];
#pragma unroll
    for (int k = 0; k < NPAIR; ++k) acc[k] = 0.0f;

    // double-buffered load pipeline: issue next iteration's 8 loads before
    // computing on the current one (16 outstanding 16B loads per lane).
    int j = chunk * TPB + tid;      // < 8192 <= D4, so first load always valid
    float4 v[NMAPS], w[NMAPS];
#pragma unroll
    for (int i = 0; i < NMAPS; ++i) v[i] = xb[(size_t)i * strideI + j];

    for (int j2 = j + JSTRIDE; j2 < D4; j2 += JSTRIDE) {
#pragma unroll
        for (int i = 0; i < NMAPS; ++i) w[i] = xb[(size_t)i * strideI + j2];
        int k = 0;
#pragma unroll
        for (int i = 0; i < NMAPS; ++i) {
#pragma unroll
            for (int jj = i; jj < NMAPS; ++jj) {
                acc[k] += v[i].x * v[jj].x + v[i].y * v[jj].y +
                          v[i].z * v[jj].z + v[i].w * v[jj].w;
                ++k;
            }
        }
#pragma unroll
        for (int i = 0; i < NMAPS; ++i) v[i] = w[i];
    }
    {   // last iteration's compute
        int k = 0;
#pragma unroll
        for (int i = 0; i < NMAPS; ++i) {
#pragma unroll
            for (int jj = i; jj < NMAPS; ++jj) {
                acc[k] += v[i].x * v[jj].x + v[i].y * v[jj].y +
                          v[i].z * v[jj].z + v[i].w * v[jj].w;
                ++k;
            }
        }
    }

    // wave (64-lane) shuffle reduction, then cross-wave LDS reduce
    const int lane = tid & 63;
    const int wave = tid >> 6;
    __shared__ float red[TPB / 64][NPAIR];
#pragma unroll
    for (int k = 0; k < NPAIR; ++k) {
        float s = acc[k];
#pragma unroll
        for (int off = 32; off > 0; off >>= 1) s += __shfl_down(s, off, 64);
        if (lane == 0) red[wave][k] = s;
    }
    __syncthreads();
    if (tid < NPAIR) {
        // layout: partial[chunk][b*36 + k]  (coalesced in finalize)
        partial[chunk * (BATCH * NPAIR) + b * NPAIR + tid] =
            red[0][tid] + red[1][tid] + red[2][tid] + red[3][tid];
    }
}

// Kernel 2: sum partials over chunks, then cosine epilogue. One block.
__global__ __launch_bounds__(256) void finalize_kernel(const float* __restrict__ partial,
                                                       float* __restrict__ out) {
    const int tid = threadIdx.x;
    __shared__ float dots_s[BATCH * NPAIR];   // [b][k], 4.6 KB
    __shared__ float norms[BATCH][NMAPS];

    for (int item = tid; item < BATCH * NPAIR; item += 256) {
        float s = 0.0f;
#pragma unroll
        for (int c = 0; c < CHUNKS; ++c) s += partial[c * (BATCH * NPAIR) + item];
        dots_s[item] = s;
    }
    __syncthreads();
    {
        int b = tid >> 3, i = tid & 7;              // 256 = 32*8 exactly
        int diag = 8 * i - (i * (i - 1)) / 2;       // upper-tri index of (i,i)
        norms[b][i] = sqrtf(dots_s[b * NPAIR + diag]);
    }
    __syncthreads();

    float sum = 0.0f;
    for (int item = tid; item < 28 * BATCH; item += 256) {
        int p = item >> 5;   // pair 0..27
        int b = item & 31;
        int i = 0, rem = p;
        while (rem >= 7 - i) { rem -= 7 - i; ++i; }
        int j = i + 1 + rem;
        int k = 8 * i - (i * (i - 1)) / 2 + (j - i);
        float d   = fabsf(dots_s[b * NPAIR + k]);
        float den = fmaxf(norms[b][i] * norms[b][j], 1e-8f);
        sum += d / den;
    }

    const int lane = tid & 63, wave = tid >> 6;
    __shared__ float red[4];
#pragma unroll
    for (int off = 32; off > 0; off >>= 1) sum += __shfl_down(sum, off, 64);
    if (lane == 0) red[wave] = sum;
    __syncthreads();
    if (tid == 0) {
        out[0] = (red[0] + red[1] + red[2] + red[3]) / (28.0f * BATCH);
    }
}

extern "C" void kernel_launch(void* const* d_in, const int* in_sizes, int n_in,
                              void* d_out, int out_size, void* d_ws, size_t ws_size,
                              hipStream_t stream) {
    const float* x       = (const float*)d_in[0];
    float*       out     = (float*)d_out;
    float*       partial = (float*)d_ws;   // CHUNKS*BATCH*NPAIR floats = 147 KB

    dim3 grid(BATCH, CHUNKS);
    gram_kernel<<<grid, TPB, 0, stream>>>(x, partial);
    finalize_kernel<<<1, 256, 0, stream>>>(partial, out);
}